// Round 1
// 539.279 us; speedup vs baseline: 1.2385x; 1.2385x over previous
//
#include <hip/hip_runtime.h>
#include <cstdint>

#define S 2048
#define D 64
#define QT 16                  // q rows per block (full 16x16 MFMA rows)
#define EPAD 8
#define ESTRIDE (S + EPAD)     // shorts; 2056*2 = 4112 B row stride (16B-divisible, 1028 dwords == 4 mod 32)

typedef __attribute__((ext_vector_type(8))) short short8;
typedef __attribute__((ext_vector_type(4))) short short4v;
typedef __attribute__((ext_vector_type(4))) float floatx4;

static __device__ __forceinline__ unsigned short f2bf(float f) {
    union { float f; uint32_t u; } v; v.f = f;
    uint32_t r = (v.u + 0x7fffu + ((v.u >> 16) & 1u)) >> 16;   // RNE
    return (unsigned short)r;
}
static __device__ __forceinline__ float bf2f(unsigned short s) {
    union { uint32_t u; float f; } v; v.u = ((uint32_t)s) << 16;
    return v.f;
}

// ---- pre-pass 1: flat fp32 -> bf16 (for K) ----
__global__ void convert_bf16_kernel(const float* __restrict__ in,
                                    unsigned short* __restrict__ out, int n8) {
    int i = (blockIdx.x * 256 + threadIdx.x);
    if (i >= n8) return;
    const float* p = in + (size_t)i * 8;
    short8 o;
    #pragma unroll
    for (int j = 0; j < 8; ++j) o[j] = (short)f2bf(p[j]);
    *(short8*)(out + (size_t)i * 8) = o;
}

// ---- pre-pass 2: V [BH][S][D] fp32 -> Vt [BH][D][S] bf16 ----
__global__ void transpose_v_kernel(const float* __restrict__ v,
                                   unsigned short* __restrict__ vt) {
    __shared__ unsigned short tile[64][72];
    const int tid = threadIdx.x;
    const int bh = blockIdx.x >> 5;        // S/64 = 32 tiles per bh
    const int s0 = (blockIdx.x & 31) * 64;
    #pragma unroll
    for (int rep = 0; rep < 16; ++rep) {
        int idx = rep * 256 + tid;
        int sl = idx >> 6, d = idx & 63;
        tile[sl][d] = f2bf(v[((size_t)bh * S + s0 + sl) * D + d]);
    }
    __syncthreads();
    #pragma unroll
    for (int rep = 0; rep < 16; ++rep) {
        int idx = rep * 256 + tid;
        int d = idx >> 6, sl = idx & 63;
        vt[((size_t)bh * D + d) * S + s0 + sl] = tile[sl][d];
    }
}

// Swapped-operand attention: QK^T computed as mfma(A=K, B=Q) so each lane's
// C fragment holds 4 CONSECUTIVE k-columns of ONE q-row (l16). Bias becomes a
// dwordx4 load, e-store a ds_write_b64, all 64 lanes active.
template <bool PRE>
__global__ __launch_bounds__(512, 4)
void attn_kernel(const float* __restrict__ q,
                 const float* __restrict__ k,
                 const float* __restrict__ v,
                 const float* __restrict__ bias,
                 const unsigned short* __restrict__ kb16,  // [BH][S][D] bf16
                 const unsigned short* __restrict__ vt16,  // [BH][D][S] bf16
                 float* __restrict__ gout,   // [BH][S][D]
                 float* __restrict__ wout)   // [BH][S][S]
{
    __shared__ __align__(16) unsigned short Elds[QT][ESTRIDE];
    __shared__ __align__(16) float pacc[QT][D];   // PV partials from k-half 1
    __shared__ float rowsum[QT];

    const int tid  = threadIdx.x;
    const int wv   = tid >> 6;      // 0..7
    const int lane = tid & 63;
    const int quad = lane >> 4;
    const int l16  = lane & 15;

    const int bh = blockIdx.x >> 7;        // / (S/QT) = /128
    const int qt = blockIdx.x & 127;
    const int q0 = qt * QT;

    if (tid < QT) rowsum[tid] = 0.0f;
    __syncthreads();

    // ---- Q fragment (B operand): lane l16 -> q row q0+l16, elems quad*8+j (+s*32) ----
    short8 bq[2];
    {
        const float* qrow = q + ((size_t)bh * S + q0 + l16) * D;
        #pragma unroll
        for (int s = 0; s < 2; ++s) {
            const float* p = qrow + s * 32 + quad * 8;
            #pragma unroll
            for (int j = 0; j < 8; ++j) bq[s][j] = (short)f2bf(p[j]);
        }
    }

    const float* brow = bias + ((size_t)bh * S + q0 + l16) * S;

    // ---- QK^T + gaussian bias + exp; wave wv handles keys t*128 + wv*16 ----
    float psum = 0.0f;
    for (int t = 0; t < 16; ++t) {
        const int kb = t * 128 + wv * 16;
        short8 ak[2];                       // A operand: lane l16 -> k row kb+l16
        if (PRE) {
            const unsigned short* kr = kb16 + ((size_t)bh * S + kb + l16) * D;
            ak[0] = *(const short8*)(kr + quad * 8);
            ak[1] = *(const short8*)(kr + 32 + quad * 8);
        } else {
            const float* krow = k + ((size_t)bh * S + kb + l16) * D;
            #pragma unroll
            for (int s = 0; s < 2; ++s) {
                const float* p = krow + s * 32 + quad * 8;
                #pragma unroll
                for (int j = 0; j < 8; ++j) ak[s][j] = (short)f2bf(p[j]);
            }
        }
        floatx4 c = {0.f, 0.f, 0.f, 0.f};
        c = __builtin_amdgcn_mfma_f32_16x16x32_bf16(ak[0], bq[0], c, 0, 0, 0);
        c = __builtin_amdgcn_mfma_f32_16x16x32_bf16(ak[1], bq[1], c, 0, 0, 0);
        // C layout: row(m) = k index = quad*4+r, col(n) = q row = l16
        const floatx4 b4 = *(const floatx4*)(brow + kb + quad * 4);
        short4v ev;
        #pragma unroll
        for (int r = 0; r < 4; ++r) {
            const float logit = c[r] * 0.125f - 0.5f * b4[r] * b4[r];
            const float e = __expf(logit);
            psum += e;
            ev[r] = (short)f2bf(e);
        }
        *(short4v*)&Elds[l16][kb + quad * 4] = ev;   // 8B store, 8B-aligned
    }
    // rowsum for q-row l16: reduce across the 4 quads, then cross-wave atomic
    psum += __shfl_xor(psum, 16);
    psum += __shfl_xor(psum, 32);
    if (lane < 16) atomicAdd(&rowsum[l16], psum);

    __syncthreads();

    // ---- write normalized weights: 32 threads per row, dwordx4 stores ----
    {
        const int r = tid >> 5;          // 0..15
        const int l = tid & 31;
        const float rinv = 1.0f / rowsum[r];
        float* wrow = wout + ((size_t)bh * S + q0 + r) * S;
        #pragma unroll 4
        for (int it = 0; it < 16; ++it) {
            const int col = it * 128 + l * 4;
            short4v evv = *(const short4v*)&Elds[r][col];
            floatx4 o;
            #pragma unroll
            for (int j = 0; j < 4; ++j) o[j] = bf2f((unsigned short)evv[j]) * rinv;
            *(floatx4*)(wrow + col) = o;
        }
    }

    // ---- PV: wave wv -> dim tile (wv&3)*16, k-half (wv>>2) ----
    {
        const int dt = wv & 3;
        const int kh = wv >> 2;
        const int dimc = dt * 16 + l16;
        floatx4 acc = {0.f, 0.f, 0.f, 0.f};
        if (PRE) {
            const unsigned short* vrow = vt16 + ((size_t)bh * D + dimc) * S + kh * 1024;
            const unsigned short* erow = &Elds[l16][kh * 1024];
            for (int sl = 0; sl < 32; ++sl) {
                const int sb = sl * 32 + quad * 8;
                short8 af  = *(const short8*)(erow + sb);
                short8 bfv = *(const short8*)(vrow + sb);
                acc = __builtin_amdgcn_mfma_f32_16x16x32_bf16(af, bfv, acc, 0, 0, 0);
            }
        } else {
            const float* vcol = v + (size_t)bh * S * D + dimc;
            for (int sl = 0; sl < 32; ++sl) {
                const int sb = kh * 1024 + sl * 32 + quad * 8;
                short8 af = *(const short8*)&Elds[l16][sb];
                short8 bfv;
                #pragma unroll
                for (int j = 0; j < 8; ++j)
                    bfv[j] = (short)f2bf(vcol[(size_t)(sb + j) * D]);
                acc = __builtin_amdgcn_mfma_f32_16x16x32_bf16(af, bfv, acc, 0, 0, 0);
            }
        }
        // C layout: row(m) = q row = quad*4+r, col(n) = dim = dimc
        if (kh == 1) {
            #pragma unroll
            for (int r = 0; r < 4; ++r) pacc[quad * 4 + r][dimc] = acc[r];
        }
        __syncthreads();
        if (kh == 0) {
            #pragma unroll
            for (int r = 0; r < 4; ++r) {
                const int row = quad * 4 + r;
                const float rinv = 1.0f / rowsum[row];
                gout[((size_t)bh * S + q0 + row) * D + dimc] =
                    (acc[r] + pacc[row][dimc]) * rinv;
            }
        }
    }
}

extern "C" void kernel_launch(void* const* d_in, const int* in_sizes, int n_in,
                              void* d_out, int out_size, void* d_ws, size_t ws_size,
                              hipStream_t stream) {
    const float* q    = (const float*)d_in[0];
    const float* k    = (const float*)d_in[1];
    const float* v    = (const float*)d_in[2];
    const float* bias = (const float*)d_in[3];
    const int BH = in_sizes[0] / (S * D);          // 16
    float* gout = (float*)d_out;
    float* wout = gout + (size_t)BH * S * D;

    const size_t nkv = (size_t)BH * S * D;         // 2,097,152 elements
    const bool pre = ws_size >= nkv * 2 * sizeof(unsigned short);

    dim3 grid(BH * (S / QT));                      // 2048 blocks

    if (pre) {
        unsigned short* kb16 = (unsigned short*)d_ws;
        unsigned short* vt16 = kb16 + nkv;
        int n8 = (int)(nkv / 8);
        convert_bf16_kernel<<<(n8 + 255) / 256, 256, 0, stream>>>(k, kb16, n8);
        transpose_v_kernel<<<BH * (S / 64), 256, 0, stream>>>(v, vt16);
        attn_kernel<true><<<grid, dim3(512), 0, stream>>>(q, k, v, bias, kb16, vt16, gout, wout);
    } else {
        attn_kernel<false><<<grid, dim3(512), 0, stream>>>(q, k, v, bias, nullptr, nullptr, gout, wout);
    }
}